// Round 3
// baseline (427.610 us; speedup 1.0000x reference)
//
#include <hip/hip_runtime.h>

// CapsuleNet forward, fully fused, fp32 — wave-per-output-capsule decomposition.
//
// Block: 640 threads = 10 waves, wave o owns output capsule o, for M=4 batches.
// Lane layout: lane = ig*16 + d,  ig in [0,4), d in [0,16).
//   Lane (ig,d) owns priors P[m][k] for i = 4k+ig (k=0..8), output dim d.
//
// R2 lesson: __shfl_xor is a DS-pipe op (ds_swizzle/bpermute); ~650 DS ops/thread
// serialized the CU's single LDS pipe (~270us of DS time matched the 350us measured).
// R3: all intra-16-lane reductions are DPP (VALU pipe):
//   sum16 = quad_perm xor1, quad_perm xor2, row_half_mirror, row_mirror
// caps reads halved via row_ror:8 half-exchange; softmax normalized in place.

constexpr int OC = 10, NI = 36, OD = 16, IL = 8;
constexpr int M  = 4;              // batches per block
constexpr int NT = 64 * OC;        // 640 threads

template<int CTRL>
__device__ __forceinline__ float dpp_movf(float v) {
    return __int_as_float(__builtin_amdgcn_update_dpp(
        0, __float_as_int(v), CTRL, 0xF, 0xF, true));
}
template<int CTRL>
__device__ __forceinline__ float dpp_add(float v) {
    return v + dpp_movf<CTRL>(v);
}
// Full sum over each 16-lane row, result in every lane. Pure VALU.
__device__ __forceinline__ float rowsum16(float v) {
    v = dpp_add<0xB1>(v);    // quad_perm [1,0,3,2]  : pair sums
    v = dpp_add<0x4E>(v);    // quad_perm [2,3,0,1]  : quad sums
    v = dpp_add<0x141>(v);   // row_half_mirror (l^7): 8-group sums
    v = dpp_add<0x140>(v);   // row_mirror    (l^15) : 16-row sum
    return v;
}

__global__ __launch_bounds__(NT, 6)
void capsnet_kernel(const float* __restrict__ xg,
                    const float* __restrict__ cwg,
                    const float* __restrict__ lwg,
                    float* __restrict__ outg)
{
    __shared__ float xs[M * 9];
    __shared__ float cw[288];
    __shared__ float caps[M * NI * IL];   // [m][i][l]
    __shared__ float pl[M * OC * NI];     // softmax state [m][o][i] (normalized in place)
    __shared__ float dl[M * OC * NI];     // exp(delta) staging for iter-1 agreement

    const int t  = threadIdx.x;
    const int b0 = blockIdx.x * M;

    if (t < M * 9) xs[t] = xg[b0 * 9 + t];
    if (t < 288)   cw[t] = cwg[t];
    __syncthreads();

    // ---- conv (1->32ch, 3x3, pad 1) + squash over capsule length -> caps ----
    if (t < M * NI) {
        const int m  = t / NI;
        const int ci = t % NI;
        const int cg = ci & 3;
        const int wx = (ci >> 2) % 3;
        const int hx = ci / 12;
        float acc[IL] = {};
        #pragma unroll
        for (int kh = 0; kh < 3; ++kh) {
            const int xh = hx + kh - 1;
            if (xh < 0 || xh > 2) continue;
            #pragma unroll
            for (int kw = 0; kw < 3; ++kw) {
                const int xw = wx + kw - 1;
                if (xw < 0 || xw > 2) continue;
                const float xv = xs[m * 9 + xh * 3 + xw];
                #pragma unroll
                for (int l = 0; l < IL; ++l)
                    acc[l] += xv * cw[(cg * 8 + l) * 9 + kh * 3 + kw];
            }
        }
        float n2 = 0.f;
        #pragma unroll
        for (int l = 0; l < IL; ++l) n2 += acc[l] * acc[l];
        const float sc = n2 / (1.f + n2) * rsqrtf(n2 + 1e-8f);
        #pragma unroll
        for (int l = 0; l < IL; ++l) caps[t * IL + l] = acc[l] * sc;
    }
    __syncthreads();

    const int o    = t >> 6;      // wave id == output capsule
    const int lane = t & 63;
    const int ig   = lane >> 4;   // i-subgroup: i = 4k + ig
    const int d    = lane & 15;   // output dim
    const int q    = d >> 3;      // which caps half (4 floats) this lane loads

    // ---- priors: P[m][k] = sum_l w[o][4k+ig][d][l] * caps[m][4k+ig][l] ----
    // Lane loads only caps half q (1 x b128); partner half arrives via row_ror:8
    // (lane d^8 in the same 16-row holds the other half). The w halves are loaded
    // own-half-first by address math, so no per-lane selects are needed.
    float P[M][9];
    #pragma unroll
    for (int k = 0; k < 9; ++k) {     // FULL unroll: P must stay in registers
        const int i = 4 * k + ig;
        const float* wp = lwg + ((o * NI + i) * OD + d) * IL;
        const float4 wq = *reinterpret_cast<const float4*>(wp + q * 4);        // own half
        const float4 wr = *reinterpret_cast<const float4*>(wp + (q ^ 1) * 4);  // other half
        #pragma unroll
        for (int m = 0; m < M; ++m) {
            const float4 co = *reinterpret_cast<const float4*>(
                &caps[(m * NI + i) * IL + q * 4]);
            float4 cx;                           // partner lane (d^8)'s half
            cx.x = dpp_movf<0x128>(co.x);        // row_ror:8
            cx.y = dpp_movf<0x128>(co.y);
            cx.z = dpp_movf<0x128>(co.z);
            cx.w = dpp_movf<0x128>(co.w);
            P[m][k] = wq.x * co.x + wq.y * co.y + wq.z * co.z + wq.w * co.w
                    + wr.x * cx.x + wr.y * cx.y + wr.z * cx.z + wr.w * cx.w;
        }
    }

    float ov[M];

    // ---- routing iteration 0: p = 0.1 uniform (softmax of zero logits) ----
    #pragma unroll
    for (int m = 0; m < M; ++m) {
        float s = 0.f;
        #pragma unroll
        for (int k = 0; k < 9; ++k) s += P[m][k];
        s *= 0.1f;
        s += __shfl_xor(s, 16);
        s += __shfl_xor(s, 32);
        const float n2 = rowsum16(s * s);
        const float sc = n2 / (1.f + n2) * rsqrtf(n2 + 1e-8f);
        ov[m] = s * sc;
    }
    // agreement -> pl = exp(delta)   (uniform prior cancels in softmax)
    #pragma unroll
    for (int m = 0; m < M; ++m) {
        #pragma unroll
        for (int k = 0; k < 9; ++k) {
            const float a = rowsum16(P[m][k] * ov[m]);
            if (d == 0) pl[(m * OC + o) * NI + 4 * k + ig] = __expf(a);
        }
    }
    __syncthreads();
    // norm1: pl <- pl / sum_o pl   (in place; 144 threads)
    if (t < M * NI) {
        const int m = t / NI, i = t % NI;
        float v[OC]; float ss = 0.f;
        #pragma unroll
        for (int oo = 0; oo < OC; ++oo) { v[oo] = pl[(m * OC + oo) * NI + i]; ss += v[oo]; }
        const float inv = 1.f / ss;
        #pragma unroll
        for (int oo = 0; oo < OC; ++oo) pl[(m * OC + oo) * NI + i] = v[oo] * inv;
    }
    __syncthreads();

    // ---- routing iteration 1 ----
    #pragma unroll
    for (int m = 0; m < M; ++m) {
        float s = 0.f;
        #pragma unroll
        for (int k = 0; k < 9; ++k)
            s += pl[(m * OC + o) * NI + 4 * k + ig] * P[m][k];
        s += __shfl_xor(s, 16);
        s += __shfl_xor(s, 32);
        const float n2 = rowsum16(s * s);
        const float sc = n2 / (1.f + n2) * rsqrtf(n2 + 1e-8f);
        ov[m] = s * sc;
    }
    // agreement -> dl = exp(delta); combined with pl in norm2
    #pragma unroll
    for (int m = 0; m < M; ++m) {
        #pragma unroll
        for (int k = 0; k < 9; ++k) {
            const float a = rowsum16(P[m][k] * ov[m]);
            if (d == 0) dl[(m * OC + o) * NI + 4 * k + ig] = __expf(a);
        }
    }
    __syncthreads();
    // norm2: pl <- (pl*dl) / sum_o (pl*dl)
    if (t < M * NI) {
        const int m = t / NI, i = t % NI;
        float v[OC]; float ss = 0.f;
        #pragma unroll
        for (int oo = 0; oo < OC; ++oo) {
            v[oo] = pl[(m * OC + oo) * NI + i] * dl[(m * OC + oo) * NI + i];
            ss += v[oo];
        }
        const float inv = 1.f / ss;
        #pragma unroll
        for (int oo = 0; oo < OC; ++oo) pl[(m * OC + oo) * NI + i] = v[oo] * inv;
    }
    __syncthreads();

    // ---- routing iteration 2 (final): emit out ----
    #pragma unroll
    for (int m = 0; m < M; ++m) {
        float s = 0.f;
        #pragma unroll
        for (int k = 0; k < 9; ++k)
            s += pl[(m * OC + o) * NI + 4 * k + ig] * P[m][k];
        s += __shfl_xor(s, 16);
        s += __shfl_xor(s, 32);
        const float n2 = rowsum16(s * s);
        const float sc = n2 / (1.f + n2) * rsqrtf(n2 + 1e-8f);
        if (ig == 0) outg[(b0 + m) * (OC * OD) + o * OD + d] = s * sc;
    }
}

extern "C" void kernel_launch(void* const* d_in, const int* in_sizes, int n_in,
                              void* d_out, int out_size, void* d_ws, size_t ws_size,
                              hipStream_t stream) {
    const float* x  = (const float*)d_in[0];   // [B,1,3,3]
    const float* cwp = (const float*)d_in[1];  // [32,1,3,3]
    const float* lw = (const float*)d_in[2];   // [10,36,16,8]
    float* out = (float*)d_out;                // [B,10,16]
    const int B = in_sizes[0] / 9;             // 16384
    dim3 grid(B / M), block(NT);
    capsnet_kernel<<<grid, block, 0, stream>>>(x, cwp, lw, out);
}

// Round 4
// 254.989 us; speedup vs baseline: 1.6770x; 1.6770x over previous
//
#include <hip/hip_runtime.h>

// CapsuleNet forward, fully fused, fp32 — wave-per-output-capsule decomposition.
//
// Block: 640 threads = 10 waves, wave o owns output capsule o, for M=4 batches.
// Lane layout: lane = ig*16 + d,  ig in [0,4), d in [0,16).
//   Lane (ig,d) owns priors P[m][k] for i = 4k+ig (k=0..8), output dim d.
//
// Hard-won lessons encoded here:
//  R1/R3: any loop indexing a register array MUST be unrolled at SOURCE level.
//    "#pragma unroll" silently fails when the body contains convergent intrinsics
//    (DPP), leaving the array runtime-indexed -> scratch (935 MB spill, 40 VGPR).
//    All P/ov/v-indexing loops below are macro-expanded; indices are literals.
//  R2: __shfl_xor is DS-pipe (ds_swizzle); ~650 DS ops/thread serialized the CU
//    LDS pipe. Intra-16-lane reductions now use DPP (VALU pipe): rowsum16.
//    Only 24 cross-row shuffles (xor 16/32) per thread remain on DS.

constexpr int OC = 10, NI = 36, OD = 16, IL = 8;
constexpr int M  = 4;              // batches per block
constexpr int NT = 64 * OC;        // 640 threads

template<int CTRL>
__device__ __forceinline__ float dpp_movf(float v) {
    return __int_as_float(__builtin_amdgcn_update_dpp(
        0, __float_as_int(v), CTRL, 0xF, 0xF, true));
}
// Full sum over each 16-lane row, result in every lane. Pure VALU (no DS pipe).
__device__ __forceinline__ float rowsum16(float v) {
    v += dpp_movf<0xB1>(v);    // quad_perm [1,0,3,2] : pair sums
    v += dpp_movf<0x4E>(v);    // quad_perm [2,3,0,1] : quad sums
    v += dpp_movf<0x141>(v);   // row_half_mirror     : 8-group sums
    v += dpp_movf<0x140>(v);   // row_mirror          : 16-row sum
    return v;
}

__global__ __launch_bounds__(NT, 5)
void capsnet_kernel(const float* __restrict__ xg,
                    const float* __restrict__ cwg,
                    const float* __restrict__ lwg,
                    float* __restrict__ outg)
{
    __shared__ float xs[M * 9];
    __shared__ float cw[288];
    __shared__ float caps[M * NI * IL];   // [m][i][l]
    __shared__ float pl[M * OC * NI];     // softmax state [m][o][i], normalized in place
    __shared__ float dl[M * OC * NI];     // exp(delta) staging for iter-1 agreement

    const int t  = threadIdx.x;
    const int b0 = blockIdx.x * M;

    if (t < M * 9) xs[t] = xg[b0 * 9 + t];
    if (t < 288)   cw[t] = cwg[t];
    __syncthreads();

    // ---- conv (1->32ch, 3x3, pad 1) + squash over capsule length -> caps ----
    // (plain pragma unroll is safe here: no convergent ops in the body; proven R2)
    if (t < M * NI) {
        const int m  = t / NI;
        const int ci = t % NI;
        const int cg = ci & 3;
        const int wx = (ci >> 2) % 3;
        const int hx = ci / 12;
        float acc[IL] = {};
        #pragma unroll
        for (int kh = 0; kh < 3; ++kh) {
            const int xh = hx + kh - 1;
            if (xh < 0 || xh > 2) continue;
            #pragma unroll
            for (int kw = 0; kw < 3; ++kw) {
                const int xw = wx + kw - 1;
                if (xw < 0 || xw > 2) continue;
                const float xv = xs[m * 9 + xh * 3 + xw];
                #pragma unroll
                for (int l = 0; l < IL; ++l)
                    acc[l] += xv * cw[(cg * 8 + l) * 9 + kh * 3 + kw];
            }
        }
        float n2 = 0.f;
        #pragma unroll
        for (int l = 0; l < IL; ++l) n2 += acc[l] * acc[l];
        const float sc = n2 / (1.f + n2) * rsqrtf(n2 + 1e-8f);
        #pragma unroll
        for (int l = 0; l < IL; ++l) caps[t * IL + l] = acc[l] * sc;
    }
    __syncthreads();

    const int o    = t >> 6;      // wave id == output capsule
    const int lane = t & 63;
    const int ig   = lane >> 4;   // i-subgroup: i = 4k + ig
    const int d    = lane & 15;   // output dim

    // ---- priors: P[m][k] = sum_l w[o][4k+ig][d][l] * caps[m][4k+ig][l] ----
    // Macro-expanded: P indices are source literals -> guaranteed VGPRs.
    float P[M][9];
    const float* wp = lwg + ((o * NI + ig) * OD + d) * IL;

#define PRI_M(k_, m_) { \
    const float4 ca = *reinterpret_cast<const float4*>(&caps[((m_) * NI + 4*(k_) + ig) * IL]); \
    const float4 cz = *reinterpret_cast<const float4*>(&caps[((m_) * NI + 4*(k_) + ig) * IL + 4]); \
    P[m_][k_] = wa.x * ca.x + wa.y * ca.y + wa.z * ca.z + wa.w * ca.w \
              + wb.x * cz.x + wb.y * cz.y + wb.z * cz.z + wb.w * cz.w; }
#define PRI_K(k_) { \
    const float4 wa = *reinterpret_cast<const float4*>(wp + (k_) * (4 * OD * IL)); \
    const float4 wb = *reinterpret_cast<const float4*>(wp + (k_) * (4 * OD * IL) + 4); \
    PRI_M(k_, 0) PRI_M(k_, 1) PRI_M(k_, 2) PRI_M(k_, 3) }
    PRI_K(0) PRI_K(1) PRI_K(2) PRI_K(3) PRI_K(4) PRI_K(5) PRI_K(6) PRI_K(7) PRI_K(8)
#undef PRI_K
#undef PRI_M

    float ov[M];

    // ---- routing iteration 0: p = 0.1 uniform (softmax of zero logits) ----
#define IT0_M(m_) { \
    float s = P[m_][0] + P[m_][1] + P[m_][2] + P[m_][3] + P[m_][4] \
            + P[m_][5] + P[m_][6] + P[m_][7] + P[m_][8]; \
    s *= 0.1f; \
    s += __shfl_xor(s, 16); \
    s += __shfl_xor(s, 32); \
    const float n2 = rowsum16(s * s); \
    const float sc = n2 / (1.f + n2) * rsqrtf(n2 + 1e-8f); \
    ov[m_] = s * sc; }
    IT0_M(0) IT0_M(1) IT0_M(2) IT0_M(3)
#undef IT0_M

    // agreement -> pl = exp(delta)  (uniform prior cancels in softmax)
#define AG_KM(m_, k_, DST) { \
    const float a = rowsum16(P[m_][k_] * ov[m_]); \
    if (d == 0) DST[((m_) * OC + o) * NI + 4*(k_) + ig] = __expf(a); }
#define AG_M(m_, DST) \
    AG_KM(m_, 0, DST) AG_KM(m_, 1, DST) AG_KM(m_, 2, DST) AG_KM(m_, 3, DST) \
    AG_KM(m_, 4, DST) AG_KM(m_, 5, DST) AG_KM(m_, 6, DST) AG_KM(m_, 7, DST) AG_KM(m_, 8, DST)
    AG_M(0, pl) AG_M(1, pl) AG_M(2, pl) AG_M(3, pl)
    __syncthreads();

    // norm1: pl <- pl / sum_o pl   (in place; 144 threads; macro-literal indices)
    if (t < M * NI) {
        float* base = &pl[(t / NI) * (OC * NI) + (t % NI)];
        float v[OC];
        float ss = 0.f;
#define LD1(oo) { v[oo] = base[(oo) * NI]; ss += v[oo]; }
        LD1(0) LD1(1) LD1(2) LD1(3) LD1(4) LD1(5) LD1(6) LD1(7) LD1(8) LD1(9)
#undef LD1
        const float inv = 1.f / ss;
#define ST1(oo) base[(oo) * NI] = v[oo] * inv;
        ST1(0) ST1(1) ST1(2) ST1(3) ST1(4) ST1(5) ST1(6) ST1(7) ST1(8) ST1(9)
#undef ST1
    }
    __syncthreads();

    // ---- routing iteration 1 ----
#define IT1_M(m_) { \
    const float* pb = &pl[((m_) * OC + o) * NI + ig]; \
    float s = pb[ 0] * P[m_][0] + pb[ 4] * P[m_][1] + pb[ 8] * P[m_][2] \
            + pb[12] * P[m_][3] + pb[16] * P[m_][4] + pb[20] * P[m_][5] \
            + pb[24] * P[m_][6] + pb[28] * P[m_][7] + pb[32] * P[m_][8]; \
    s += __shfl_xor(s, 16); \
    s += __shfl_xor(s, 32); \
    const float n2 = rowsum16(s * s); \
    const float sc = n2 / (1.f + n2) * rsqrtf(n2 + 1e-8f); \
    ov[m_] = s * sc; }
    IT1_M(0) IT1_M(1) IT1_M(2) IT1_M(3)

    // agreement -> dl = exp(delta); combined with pl in norm2
    AG_M(0, dl) AG_M(1, dl) AG_M(2, dl) AG_M(3, dl)
#undef AG_M
#undef AG_KM
    __syncthreads();

    // norm2: pl <- (pl*dl) / sum_o (pl*dl)
    if (t < M * NI) {
        const int off = (t / NI) * (OC * NI) + (t % NI);
        float* pb = &pl[off];
        const float* db = &dl[off];
        float v[OC];
        float ss = 0.f;
#define LD2(oo) { v[oo] = pb[(oo) * NI] * db[(oo) * NI]; ss += v[oo]; }
        LD2(0) LD2(1) LD2(2) LD2(3) LD2(4) LD2(5) LD2(6) LD2(7) LD2(8) LD2(9)
#undef LD2
        const float inv = 1.f / ss;
#define ST2(oo) pb[(oo) * NI] = v[oo] * inv;
        ST2(0) ST2(1) ST2(2) ST2(3) ST2(4) ST2(5) ST2(6) ST2(7) ST2(8) ST2(9)
#undef ST2
    }
    __syncthreads();

    // ---- routing iteration 2 (final): emit out ----
#define IT2_M(m_) { \
    const float* pb = &pl[((m_) * OC + o) * NI + ig]; \
    float s = pb[ 0] * P[m_][0] + pb[ 4] * P[m_][1] + pb[ 8] * P[m_][2] \
            + pb[12] * P[m_][3] + pb[16] * P[m_][4] + pb[20] * P[m_][5] \
            + pb[24] * P[m_][6] + pb[28] * P[m_][7] + pb[32] * P[m_][8]; \
    s += __shfl_xor(s, 16); \
    s += __shfl_xor(s, 32); \
    const float n2 = rowsum16(s * s); \
    const float sc = n2 / (1.f + n2) * rsqrtf(n2 + 1e-8f); \
    if (ig == 0) outg[(b0 + (m_)) * (OC * OD) + o * OD + d] = s * sc; }
    IT2_M(0) IT2_M(1) IT2_M(2) IT2_M(3)
#undef IT2_M
#undef IT1_M
}

extern "C" void kernel_launch(void* const* d_in, const int* in_sizes, int n_in,
                              void* d_out, int out_size, void* d_ws, size_t ws_size,
                              hipStream_t stream) {
    const float* x  = (const float*)d_in[0];   // [B,1,3,3]
    const float* cwp = (const float*)d_in[1];  // [32,1,3,3]
    const float* lw = (const float*)d_in[2];   // [10,36,16,8]
    float* out = (float*)d_out;                // [B,10,16]
    const int B = in_sizes[0] / 9;             // 16384
    dim3 grid(B / M), block(NT);
    capsnet_kernel<<<grid, block, 0, stream>>>(x, cwp, lw, out);
}

// Round 5
// 238.226 us; speedup vs baseline: 1.7950x; 1.0704x over previous
//
#include <hip/hip_runtime.h>

// CapsuleNet forward, fully fused, fp32 — wave-per-output-capsule decomposition.
//
// Block: 640 threads = 10 waves, wave o owns output capsule o, for M=4 batches.
// Lane layout: lane = ig*16 + d,  ig in [0,4), d in [0,16).
//   Lane (ig,d) owns priors P[m][k] for i = 4k+ig (k=0..8), output dim d.
//
// Hard-won lessons encoded here:
//  R1/R3: loops indexing register arrays MUST be source-level (macro) unrolled.
//    "#pragma unroll" silently fails with convergent intrinsics (DPP) in the
//    body -> runtime indexing -> scratch spill (935 MB). Macros only.
//  R2: __shfl_xor is DS-pipe; intra-16-lane reductions use DPP (VALU pipe).
//  R4: DS pipe (1/CU, shared by ~30 waves) was the limiter (~1.9k cy/wave).
//    R5 cuts DS wave-instrs ~40%:
//      - caps reads halved via row_ror:8 half-exchange (R3-proven math)
//      - pl/dl k-contiguous [m][o][ig][12] -> b128 reads/writes
//      - exp moved from 10-wave agreement phase to 3-wave norm phase

constexpr int OC = 10, NI = 36, OD = 16, IL = 8;
constexpr int M  = 4;              // batches per block
constexpr int NT = 64 * OC;        // 640 threads
constexpr int PROW = 12;           // padded k-row stride (floats): 16B-aligned b128

template<int CTRL>
__device__ __forceinline__ float dpp_movf(float v) {
    return __int_as_float(__builtin_amdgcn_update_dpp(
        0, __float_as_int(v), CTRL, 0xF, 0xF, true));
}
// Full sum over each 16-lane row, result in every lane. Pure VALU (no DS pipe).
__device__ __forceinline__ float rowsum16(float v) {
    v += dpp_movf<0xB1>(v);    // quad_perm [1,0,3,2] : pair sums
    v += dpp_movf<0x4E>(v);    // quad_perm [2,3,0,1] : quad sums
    v += dpp_movf<0x141>(v);   // row_half_mirror     : 8-group sums
    v += dpp_movf<0x140>(v);   // row_mirror          : 16-row sum
    return v;
}

__global__ __launch_bounds__(NT, 5)
void capsnet_kernel(const float* __restrict__ xg,
                    const float* __restrict__ cwg,
                    const float* __restrict__ lwg,
                    float* __restrict__ outg)
{
    __shared__ float xs[M * 9];
    __shared__ float cw[288];
    __shared__ float caps[M * NI * IL];        // [m][i][l]
    __shared__ float pl[M * OC * 4 * PROW];    // [m][o][ig][12]: probs / raw deltas
    __shared__ float dl[M * OC * 4 * PROW];    // raw delta staging for iter-1

    const int t  = threadIdx.x;
    const int b0 = blockIdx.x * M;

    if (t < M * 9) xs[t] = xg[b0 * 9 + t];
    if (t < 288)   cw[t] = cwg[t];
    __syncthreads();

    // ---- conv (1->32ch, 3x3, pad 1) + squash over capsule length -> caps ----
    if (t < M * NI) {
        const int m  = t / NI;
        const int ci = t % NI;
        const int cg = ci & 3;
        const int wx = (ci >> 2) % 3;
        const int hx = ci / 12;
        float acc[IL] = {};
        #pragma unroll
        for (int kh = 0; kh < 3; ++kh) {
            const int xh = hx + kh - 1;
            if (xh < 0 || xh > 2) continue;
            #pragma unroll
            for (int kw = 0; kw < 3; ++kw) {
                const int xw = wx + kw - 1;
                if (xw < 0 || xw > 2) continue;
                const float xv = xs[m * 9 + xh * 3 + xw];
                #pragma unroll
                for (int l = 0; l < IL; ++l)
                    acc[l] += xv * cw[(cg * 8 + l) * 9 + kh * 3 + kw];
            }
        }
        float n2 = 0.f;
        #pragma unroll
        for (int l = 0; l < IL; ++l) n2 += acc[l] * acc[l];
        const float sc = n2 / (1.f + n2) * rsqrtf(n2 + 1e-8f);
        #pragma unroll
        for (int l = 0; l < IL; ++l) caps[t * IL + l] = acc[l] * sc;
    }
    __syncthreads();

    const int o    = t >> 6;      // wave id == output capsule
    const int lane = t & 63;
    const int ig   = lane >> 4;   // i-subgroup: i = 4k + ig
    const int d    = lane & 15;   // output dim
    const int q    = d >> 3;      // caps half this lane loads (partner = d^8)

    // ---- priors: P[m][k] = sum_l w[o][4k+ig][d][l] * caps[m][4k+ig][l] ----
    // Lane loads only caps half q (1 x b128); partner half via row_ror:8 DPP
    // (lane d^8 holds the other half; math HW-proven in R3). Own-half-first w
    // addressing avoids per-lane selects. Macro-expanded: literal indices only.
    float P[M][9];
    const float* wp = lwg + ((o * NI + ig) * OD + d) * IL;
    const int qo = q * 4, qx = (q ^ 1) * 4;

#define PRI_M(k_, m_) { \
    const float4 co = *reinterpret_cast<const float4*>( \
        &caps[((m_) * NI + 4*(k_) + ig) * IL + qo]); \
    float4 cx; \
    cx.x = dpp_movf<0x128>(co.x); \
    cx.y = dpp_movf<0x128>(co.y); \
    cx.z = dpp_movf<0x128>(co.z); \
    cx.w = dpp_movf<0x128>(co.w); \
    P[m_][k_] = wq.x * co.x + wq.y * co.y + wq.z * co.z + wq.w * co.w \
              + wr.x * cx.x + wr.y * cx.y + wr.z * cx.z + wr.w * cx.w; }
#define PRI_K(k_) { \
    const float4 wq = *reinterpret_cast<const float4*>(wp + (k_) * (4 * OD * IL) + qo); \
    const float4 wr = *reinterpret_cast<const float4*>(wp + (k_) * (4 * OD * IL) + qx); \
    PRI_M(k_, 0) PRI_M(k_, 1) PRI_M(k_, 2) PRI_M(k_, 3) }
    PRI_K(0) PRI_K(1) PRI_K(2) PRI_K(3) PRI_K(4) PRI_K(5) PRI_K(6) PRI_K(7) PRI_K(8)
#undef PRI_K
#undef PRI_M

    float ov[M];

    // ---- routing iteration 0: p = 0.1 uniform (softmax of zero logits) ----
#define IT0_M(m_) { \
    float s = P[m_][0] + P[m_][1] + P[m_][2] + P[m_][3] + P[m_][4] \
            + P[m_][5] + P[m_][6] + P[m_][7] + P[m_][8]; \
    s *= 0.1f; \
    s += __shfl_xor(s, 16); \
    s += __shfl_xor(s, 32); \
    const float n2 = rowsum16(s * s); \
    const float sc = n2 / (1.f + n2) * rsqrtf(n2 + 1e-8f); \
    ov[m_] = s * sc; }
    IT0_M(0) IT0_M(1) IT0_M(2) IT0_M(3)
#undef IT0_M

    // agreement -> DST raw deltas, packed b128 writes from lane d==0 of each row.
    // exp is applied later in the (cheap, 3-wave) norm phase.
#define AG_M(m_, DST) { \
    const float a0 = rowsum16(P[m_][0] * ov[m_]); \
    const float a1 = rowsum16(P[m_][1] * ov[m_]); \
    const float a2 = rowsum16(P[m_][2] * ov[m_]); \
    const float a3 = rowsum16(P[m_][3] * ov[m_]); \
    const float a4 = rowsum16(P[m_][4] * ov[m_]); \
    const float a5 = rowsum16(P[m_][5] * ov[m_]); \
    const float a6 = rowsum16(P[m_][6] * ov[m_]); \
    const float a7 = rowsum16(P[m_][7] * ov[m_]); \
    const float a8 = rowsum16(P[m_][8] * ov[m_]); \
    if (d == 0) { \
        float* wb = &DST[(((m_) * OC + o) * 4 + ig) * PROW]; \
        *reinterpret_cast<float4*>(wb)     = make_float4(a0, a1, a2, a3); \
        *reinterpret_cast<float4*>(wb + 4) = make_float4(a4, a5, a6, a7); \
        wb[8] = a8; \
    } }
    AG_M(0, pl) AG_M(1, pl) AG_M(2, pl) AG_M(3, pl)
    __syncthreads();

    // norm1: pl <- softmax_o(exp(raw delta))   (144 threads; literal indices)
    if (t < M * NI) {
        const int m = t / NI, r = t % NI;
        float* base = &pl[(m * OC * 4 + (r / 9)) * PROW + (r % 9)];
        float v[OC];
        float ss = 0.f;
#define LD1(oo) { v[oo] = __expf(base[(oo) * 4 * PROW]); ss += v[oo]; }
        LD1(0) LD1(1) LD1(2) LD1(3) LD1(4) LD1(5) LD1(6) LD1(7) LD1(8) LD1(9)
#undef LD1
        const float inv = 1.f / ss;
#define ST1(oo) base[(oo) * 4 * PROW] = v[oo] * inv;
        ST1(0) ST1(1) ST1(2) ST1(3) ST1(4) ST1(5) ST1(6) ST1(7) ST1(8) ST1(9)
#undef ST1
    }
    __syncthreads();

    // ---- routing iteration 1 ----
#define IT1_M(m_) { \
    const float* pb = &pl[(((m_) * OC + o) * 4 + ig) * PROW]; \
    const float4 pA = *reinterpret_cast<const float4*>(pb); \
    const float4 pB = *reinterpret_cast<const float4*>(pb + 4); \
    const float p8  = pb[8]; \
    float s = pA.x * P[m_][0] + pA.y * P[m_][1] + pA.z * P[m_][2] + pA.w * P[m_][3] \
            + pB.x * P[m_][4] + pB.y * P[m_][5] + pB.z * P[m_][6] + pB.w * P[m_][7] \
            + p8   * P[m_][8]; \
    s += __shfl_xor(s, 16); \
    s += __shfl_xor(s, 32); \
    const float n2 = rowsum16(s * s); \
    const float sc = n2 / (1.f + n2) * rsqrtf(n2 + 1e-8f); \
    ov[m_] = s * sc; }
    IT1_M(0) IT1_M(1) IT1_M(2) IT1_M(3)

    // agreement -> dl raw deltas; combined with pl in norm2
    AG_M(0, dl) AG_M(1, dl) AG_M(2, dl) AG_M(3, dl)
#undef AG_M
    __syncthreads();

    // norm2: pl <- softmax_o(pl * exp(dl))
    if (t < M * NI) {
        const int m = t / NI, r = t % NI;
        const int off = (m * OC * 4 + (r / 9)) * PROW + (r % 9);
        float* pb = &pl[off];
        const float* db = &dl[off];
        float v[OC];
        float ss = 0.f;
#define LD2(oo) { v[oo] = pb[(oo) * 4 * PROW] * __expf(db[(oo) * 4 * PROW]); ss += v[oo]; }
        LD2(0) LD2(1) LD2(2) LD2(3) LD2(4) LD2(5) LD2(6) LD2(7) LD2(8) LD2(9)
#undef LD2
        const float inv = 1.f / ss;
#define ST2(oo) pb[(oo) * 4 * PROW] = v[oo] * inv;
        ST2(0) ST2(1) ST2(2) ST2(3) ST2(4) ST2(5) ST2(6) ST2(7) ST2(8) ST2(9)
#undef ST2
    }
    __syncthreads();

    // ---- routing iteration 2 (final): emit out ----
#define IT2_M(m_) { \
    const float* pb = &pl[(((m_) * OC + o) * 4 + ig) * PROW]; \
    const float4 pA = *reinterpret_cast<const float4*>(pb); \
    const float4 pB = *reinterpret_cast<const float4*>(pb + 4); \
    const float p8  = pb[8]; \
    float s = pA.x * P[m_][0] + pA.y * P[m_][1] + pA.z * P[m_][2] + pA.w * P[m_][3] \
            + pB.x * P[m_][4] + pB.y * P[m_][5] + pB.z * P[m_][6] + pB.w * P[m_][7] \
            + p8   * P[m_][8]; \
    s += __shfl_xor(s, 16); \
    s += __shfl_xor(s, 32); \
    const float n2 = rowsum16(s * s); \
    const float sc = n2 / (1.f + n2) * rsqrtf(n2 + 1e-8f); \
    if (ig == 0) outg[(b0 + (m_)) * (OC * OD) + o * OD + d] = s * sc; }
    IT2_M(0) IT2_M(1) IT2_M(2) IT2_M(3)
#undef IT2_M
#undef IT1_M
}

extern "C" void kernel_launch(void* const* d_in, const int* in_sizes, int n_in,
                              void* d_out, int out_size, void* d_ws, size_t ws_size,
                              hipStream_t stream) {
    const float* x  = (const float*)d_in[0];   // [B,1,3,3]
    const float* cwp = (const float*)d_in[1];  // [32,1,3,3]
    const float* lw = (const float*)d_in[2];   // [10,36,16,8]
    float* out = (float*)d_out;                // [B,10,16]
    const int B = in_sizes[0] / 9;             // 16384
    dim3 grid(B / M), block(NT);
    capsnet_kernel<<<grid, block, 0, stream>>>(x, cwp, lw, out);
}